// Round 20
// baseline (175.602 us; speedup 1.0000x reference)
//
#include <hip/hip_runtime.h>
#include <stdint.h>

#pragma clang fp contract(off)

#define NPRI   136500
#define BATCH  8
#define NMS_K  5000
#define NKPAD  5120      // padded row count
#define TOPK   750
#define SORT_N 8192
#define HBINS  1024      // top16 float bits of s in (0.05,1] span [0x3D4C,0x3F80]
#define HOFF   0x3D40
#define MROW   80        // u64 words per mask row (79 used, padded)
#define CNTSTRIDE 32     // 128 B between per-batch counters (line padding)
#define CUT    32        // M built only for words < CUT (cols < 2048)

typedef unsigned long long u64;

__device__ __forceinline__ u64 shfl64(u64 v, int src) {
    int lo = __shfl((int)(unsigned)(v & 0xffffffffull), src);
    int hi = __shfl((int)(unsigned)(v >> 32), src);
    return ((u64)(unsigned)hi << 32) | (u64)(unsigned)lo;
}
__device__ __forceinline__ u64 shfl64_xor(u64 v, int m) {
    int lo = __shfl_xor((int)(unsigned)(v & 0xffffffffull), m);
    int hi = __shfl_xor((int)(unsigned)(v >> 32), m);
    return ((u64)(unsigned)hi << 32) | (u64)(unsigned)lo;
}

// R12 (verified absmax=0): exact suppression test, pure f32, branchless.
// suppress <=> RN(inter/uni) > 0.3f <=> inter > (0.3f + 2^-26)*uni in reals.
// Two single-rounding FMAs: u = RN(inter-0.3f*uni); d = RN(u-2^-26*uni).
// d>0 <=> true condition (monotonicity + quantum-grid argument).
__device__ __forceinline__ bool iou_sup(float4 c4, float aj,
                                        float4 rbx, float ra) {
    float xx1 = fmaxf(c4.x, rbx.x);
    float yy1 = fmaxf(c4.y, rbx.y);
    float xx2 = fminf(c4.z, rbx.z);
    float yy2 = fminf(c4.w, rbx.w);
    float iw = fmaxf(xx2 - xx1, 0.0f);
    float ih = fmaxf(yy2 - yy1, 0.0f);
    float inter = iw * ih;
    float uni = (aj - inter) + ra;      // (area_col - inter) + area_row
    float u = fmaf(-0.3f, uni, inter);
    float d = fmaf(-1.4901161193847656e-8f, uni, u);   // 2^-26 exact in f32
    return d > 0.0f;
}
__device__ __forceinline__ u64 iou_word(float4 c4, float aj,
                                        float4 rbx, float ra) {
    return __ballot(iou_sup(c4, aj, rbx, ra));
}

// diag/below-diag mask for a word given sh = row - 64*w (wave-uniform SALU)
__device__ __forceinline__ u64 diag_mask(u64 word, int sh) {
    if (sh >= 0)
        word &= (sh >= 63) ? 0ull : (~0ull << (sh + 1));
    return word;
}

// R23 slow path (words >= CUT, typically never executed: scan ends ~word
// 13): per-lane serial row-word from cbox/carea, SAME exact test and SAME
// operand order as maskbuild => bit-identical to what maskbuild would have
// stored. rbx/ra = ROW box/area; W = column word.
__device__ u64 row_word_slow(const float4* __restrict__ cbp,
                             const float* __restrict__ cap,
                             float4 rbx, float ra, int W) {
    int jbase = W << 6;
    u64 word = 0ull;
    for (int jj = 0; jj < 64; ++jj) {
        int jc = min(jbase + jj, NMS_K - 1);
        if (iou_sup(cbp[jc], cap[jc], rbx, ra)) word |= (1ull << jj);
    }
    return word;
}

// -------- softmax score (cached to sraw) + LDS histogram of top-16 bits ---
__global__ __launch_bounds__(256) void score_hist_kernel(
        const float* __restrict__ conf, unsigned int* __restrict__ hist,
        float* __restrict__ sraw) {
    int b = blockIdx.y;
    __shared__ unsigned int h[HBINS];
    for (int i = threadIdx.x; i < HBINS; i += 256) h[i] = 0;
    __syncthreads();
    for (int p = blockIdx.x * 256 + threadIdx.x; p < NPRI; p += 64 * 256) {
        float2 c = ((const float2*)conf)[(size_t)b * NPRI + p];
        float m  = fmaxf(c.x, c.y);
        float e0 = expf(c.x - m), e1 = expf(c.y - m);
        float s  = e1 / (e0 + e1);
        sraw[(size_t)b * NPRI + p] = s;
        if (s > 0.05f) {
            int bin = (int)(__float_as_uint(s) >> 16) - HOFF;
            bin = min(max(bin, 0), HBINS - 1);
            atomicAdd(&h[bin], 1u);
        }
    }
    __syncthreads();
    for (int i = threadIdx.x; i < HBINS; i += 256) {
        unsigned int v = h[i];
        if (v) atomicAdd(&hist[b * HBINS + i], v);
    }
}

// -------- compact candidates: grid-stride, LDS staging, 1 atomic/block ----
// R21 verified core. R26: threshold bin computed IN-KERNEL per block
// (replaces scan_kernel dispatch); deterministic => output byte-identical.
__global__ __launch_bounds__(256) void compact_kernel(
        const float* __restrict__ sraw, const unsigned int* __restrict__ hist,
        u64* __restrict__ keys, unsigned int* __restrict__ cnt) {
    int b = blockIdx.y;
    int tid = threadIdx.x;
    int lane = tid & 63;
    __shared__ u64 buf[2304];           // 18 KiB; >= 9 iters * 256 worst case
    __shared__ unsigned int hsum[256];  // chunk sums -> suffix sums
    __shared__ int best_sh;
    __shared__ unsigned int nloc;
    __shared__ unsigned int base_sh;
    // ---- compute tbin (replicated; identical in all blocks) ----
    const unsigned int* hb = hist + b * HBINS;
    int t4 = tid * 4;
    unsigned int h0 = hb[t4], h1 = hb[t4 + 1], h2 = hb[t4 + 2], h3 = hb[t4 + 3];
    hsum[tid] = h0 + h1 + h2 + h3;
    if (tid == 0) { best_sh = 0; nloc = 0; }
    __syncthreads();
    for (int o = 1; o < 256; o <<= 1) {     // reverse inclusive chunk scan
        unsigned int add = (tid + o < 256) ? hsum[tid + o] : 0u;
        __syncthreads();
        hsum[tid] += add;
        __syncthreads();
    }
    unsigned int nxt = (tid + 1 < 256) ? hsum[tid + 1] : 0u;  // suffix(t4+4)
    unsigned int s3 = h3 + nxt;
    unsigned int s2 = h2 + s3;
    unsigned int s1 = h1 + s2;
    unsigned int s0 = h0 + s1;
    int cand = -1;                          // suffix non-increasing in bin
    if (s3 >= (unsigned)NMS_K) cand = t4 + 3;
    else if (s2 >= (unsigned)NMS_K) cand = t4 + 2;
    else if (s1 >= (unsigned)NMS_K) cand = t4 + 1;
    else if (s0 >= (unsigned)NMS_K) cand = t4;
    if (cand > 0) atomicMax(&best_sh, cand);
    __syncthreads();
    int tb = best_sh;
    // ---- R21 compact body ----
    for (int p = blockIdx.x * 256 + tid; p < NPRI; p += 64 * 256) {
        float s = sraw[(size_t)b * NPRI + p];
        bool pass = false;
        unsigned int bits = 0;
        if (s > 0.05f) {
            bits = __float_as_uint(s);
            int bin = (int)(bits >> 16) - HOFF;
            bin = min(max(bin, 0), HBINS - 1);
            pass = (bin >= tb);
        }
        u64 bal = __ballot(pass);
        int rank = (int)__popcll(bal & ((1ull << lane) - 1ull));
        unsigned int wbase = 0;
        if (lane == 0 && bal)
            wbase = atomicAdd(&nloc, (unsigned)__popcll(bal));
        wbase = (unsigned)__shfl((int)wbase, 0);
        if (pass)
            buf[wbase + rank] = ((u64)bits << 32) | (u64)(~(unsigned int)p);
    }
    __syncthreads();
    unsigned int tot = nloc;
    if (tid == 0)
        base_sh = tot ? atomicAdd(&cnt[b * CNTSTRIDE], tot) : 0u;
    __syncthreads();
    unsigned int base = base_sh;
    for (unsigned int i = tid; i < tot; i += 256) {
        unsigned int pos = base + i;
        if (pos < SORT_N)
            keys[(size_t)b * SORT_N + pos] = buf[i];
    }
}

// -------- R30: 4096-chunk sort = register bitonic + LDS merge-path --------
// Extends R29's verified structure from 2048 to 4096 chunks, eliminating
// merge1 (dispatch + gap + keys round-trip). 16 blocks x 1024 thr x 64 KiB
// LDS ping-pong (proven-compilable size). Stage A: 64 runs of 64 per chunk
// (register bitonic, 0 barriers). Stage B: 6 merge-path rounds 64->4096,
// 4 interleaved BRANCHLESS chains per thread (arrays + full unroll = static
// indices), per-round step count 32-clz(L) (= ceil(log2(L+1)), no dead
// steps). 7 barriers total (vs R24's 91 — not that mistake). Deterministic
// sort => keys2 holds the same 4096-desc runs merge1 produced => outputs
// byte-identical.
__global__ __launch_bounds__(1024) void sortmerge4k_kernel(
        const u64* __restrict__ keys, u64* __restrict__ keys2,
        const unsigned int* __restrict__ cnt) {
    int b = blockIdx.y, c = blockIdx.x;     // chunk 0..1 (4096 each)
    int tid = threadIdx.x;
    int lane = tid & 63;
    int wv = tid >> 6;                      // 0..15
    int n = min((int)cnt[b * CNTSTRIDE], SORT_N);
    int base = c * 4096;
    if (base >= n) {                        // all-zero chunk: skip the sort
        for (int i = tid; i < 4096; i += 1024)
            keys2[(size_t)b * SORT_N + base + i] = 0ull;
        return;
    }
    __shared__ u64 k[4096];                 // 32 KiB
    __shared__ u64 k2[4096];                // 32 KiB (ping-pong)
    // ---- stage A: 64 runs of 64, register bitonic per wave (4/wave) ----
    for (int ch = wv; ch < 64; ch += 16) {
        int idx = base + ch * 64 + lane;
        u64 v = (idx < n) ? keys[(size_t)b * SORT_N + idx] : 0ull;
#pragma unroll
        for (int kk = 2; kk <= 64; kk <<= 1) {
#pragma unroll
            for (int j = kk >> 1; j > 0; j >>= 1) {
                u64 o = shfl64_xor(v, j);
                bool low  = (lane & j) == 0;          // partner above
                bool desc = (lane & kk) == 0;         // kk=64 -> always true
                u64 mx = (v >= o) ? v : o;
                u64 mn = (v >= o) ? o : v;
                v = desc ? (low ? mx : mn) : (low ? mn : mx);
            }
        }
        k[ch * 64 + lane] = v;
    }
    __syncthreads();
    // ---- stage B: 6 merge-path rounds, 64 -> 4096, 4 chains/thread -----
    u64* src = k;
    u64* dst = k2;
#pragma unroll 1
    for (int L = 64; L < 4096; L <<= 1) {
        int oo[4], lo[4], hi[4], Ao[4];
#pragma unroll
        for (int q = 0; q < 4; ++q) {
            int o = tid + q * 1024;
            int pair = o / (2 * L);
            Ao[q] = pair * 2 * L;
            oo[q] = o - Ao[q];
            lo[q] = max(0, oo[q] - L);
            hi[q] = min(oo[q], L);
        }
        int nsteps = 32 - __builtin_clz(L); // = ceil(log2(L+1))
        for (int s = 0; s < nsteps; ++s) {
#pragma unroll
            for (int q = 0; q < 4; ++q) {
                bool lv = lo[q] < hi[q];
                int m = (lo[q] + hi[q] + 1) >> 1;
                u64 a  = src[Ao[q] + max(m - 1, 0)];
                u64 bb = src[Ao[q] + L + min(max(oo[q] - m, 0), L - 1)];
                bool ok = (oo[q] - m >= L) || (a >= bb);
                lo[q] = (lv && ok)  ? m     : lo[q];
                hi[q] = (lv && !ok) ? m - 1 : hi[q];
            }
        }
#pragma unroll
        for (int q = 0; q < 4; ++q) {
            int i = lo[q], j = oo[q] - lo[q];
            u64 v;
            if (j >= L) v = src[Ao[q] + i];
            else if (i >= L) v = src[Ao[q] + L + j];
            else {
                u64 a = src[Ao[q] + i];
                u64 bb = src[Ao[q] + L + j];
                v = (a >= bb) ? a : bb;
            }
            dst[tid + q * 1024] = v;
        }
        __syncthreads();
        u64* t = src; src = dst; dst = t;
    }
    for (int i = tid; i < 4096; i += 1024)
        keys2[(size_t)b * SORT_N + base + i] = src[i];
}

// -------- merge-path stage 2 fused with decode: (4096,4096)->rows 0..4999 -
// R30: reads keys2 (4096-desc runs) directly.
__global__ __launch_bounds__(256) void merge2_decode_kernel(
        const u64* __restrict__ keys2,
        const float* __restrict__ loc, const float* __restrict__ priors,
        float* __restrict__ cscore, float* __restrict__ cbox,
        float* __restrict__ carea) {
    int b = blockIdx.y;
    int o = blockIdx.x * 256 + threadIdx.x;   // 0..5119
    const u64* A  = keys2 + (size_t)b * SORT_N;
    const u64* Bp = A + 4096;
    int lo = max(0, o - 4096), hi = min(o, 4096);
    while (lo < hi) {
        int mid = (lo + hi + 1) >> 1;
        bool ok = (o - mid >= 4096) || (A[mid - 1] >= Bp[o - mid]);
        if (ok) lo = mid; else hi = mid - 1;
    }
    int i = lo, j = o - lo;
    u64 key;
    if (j >= 4096) key = A[i];
    else if (i >= 4096) key = Bp[j];
    else key = (A[i] >= Bp[j]) ? A[i] : Bp[j];
    if (o >= NMS_K) return;                   // only rows 0..4999 consumed
    float sc; int idx;
    if (key != 0ull) {
        sc  = __uint_as_float((unsigned int)(key >> 32));
        idx = (int)(~(unsigned int)key);
    } else { sc = -1.0f; idx = 0; }
    cscore[b * NMS_K + o] = sc;
    float x1 = 0.f, y1 = 0.f, x2 = 0.f, y2 = 0.f, ar = 0.f;
    if (key != 0ull) {
        const float* l  = loc + ((size_t)b * NPRI + idx) * 4;
        const float* pr = priors + (size_t)idx * 4;
        float lx = l[0], ly = l[1], lw = l[2], lh = l[3];
        float pcx = pr[0], pcy = pr[1], pw = pr[2], ph = pr[3];
        float cx = pcx + (lx * 0.1f) * pw;
        float cy = pcy + (ly * 0.1f) * ph;
        float wd = pw * expf(lw * 0.2f);
        float ht = ph * expf(lh * 0.2f);
        x1 = cx - wd * 0.5f;  y1 = cy - ht * 0.5f;
        x2 = x1 + wd;         y2 = y1 + ht;
        ar = (x2 - x1) * (y2 - y1);
    }
    float* cb = cbox + ((size_t)b * NMS_K + o) * 4;
    cb[0] = x1; cb[1] = y1; cb[2] = x2; cb[3] = y2;
    carea[b * NMS_K + o] = ar;
}

// -------- ROW-MAJOR upper-triangle suppression mask: M[b][row][w] --------
// R20 verified config; R23: only words < CUT built. Scan consumes words <=
// ~14 for this data; words >= CUT computed on-the-fly in maskscan if needed.
__global__ __launch_bounds__(256, 4) void maskbuild_kernel(
        const float* __restrict__ cbox, const float* __restrict__ carea,
        u64* __restrict__ M) {
    int b   = blockIdx.y;
    int bid = blockIdx.x;               // 0..71 (CUT/4 quads)
    int wgq, rb;
    if (bid >= 380) { wgq = 19; rb = bid - 380; }
    else {
        int w = (int)((sqrtf((float)(4 * bid + 5)) - 1.0f) * 0.5f);
        while (w * (w + 1) > bid) w--;
        while ((w + 1) * (w + 2) <= bid) w++;
        wgq = w; rb = bid - w * (w + 1);    // rb <= 2*wgq+1 by construction
    }
    int tid  = threadIdx.x;
    int lane = tid & 63;
    int wv   = __builtin_amdgcn_readfirstlane(tid >> 6);  // 0..3, scalar
    int w0   = wgq * 4;
    int rowbase = rb * 128;

    __shared__ float4 rbox[128];        // 2 KiB
    __shared__ float  rarea[128];       // 0.5 KiB
    if (tid < 128) {
        int i  = rowbase + tid;
        int ic = min(i, NMS_K - 1);     // rows >= NMS_K: dup, masked downstream
        rbox[tid]  = ((const float4*)cbox)[(size_t)b * NMS_K + ic];
        rarea[tid] = carea[(size_t)b * NMS_K + ic];
    }
    // 4 column-words in registers: lane = column j of word w0+k
    const float4* __restrict__ cbp = (const float4*)cbox + (size_t)b * NMS_K;
    const float*  __restrict__ cap = carea + (size_t)b * NMS_K;
    int j0 = w0 * 64 + lane;
    float4 c4_0 = cbp[min(j0,       NMS_K - 1)];
    float4 c4_1 = cbp[min(j0 +  64, NMS_K - 1)];
    float4 c4_2 = cbp[min(j0 + 128, NMS_K - 1)];
    float4 c4_3 = cbp[min(j0 + 192, NMS_K - 1)];
    float aj0 = cap[min(j0,       NMS_K - 1)];
    float aj1 = cap[min(j0 +  64, NMS_K - 1)];
    float aj2 = cap[min(j0 + 128, NMS_K - 1)];
    float aj3 = cap[min(j0 + 192, NMS_K - 1)];
    __syncthreads();                    // the only barrier; exits below OK

    int lr0 = 32 * wv;                  // this wave's local row base
    int rglob0 = rowbase + lr0;
    if (rglob0 >= NMS_K) return;        // wave entirely past the last row

    u64* __restrict__ Mb = M + (size_t)b * NKPAD * MROW;  // row-major

    if (rglob0 + 31 < w0 * 64) {
        // ---- pure-upper fast path: no diag masking, fixed 16-pair trip.
#pragma unroll 2
        for (int q = 0; q < 32; q += 2) {
            int lr = lr0 + q;
            float4 rb0 = rbox[lr], rb1 = rbox[lr + 1];
            float  ra0 = rarea[lr], ra1 = rarea[lr + 1];
            u64 A0 = iou_word(c4_0, aj0, rb0, ra0);
            u64 B0 = iou_word(c4_0, aj0, rb1, ra1);
            u64 A1 = iou_word(c4_1, aj1, rb0, ra0);
            u64 B1 = iou_word(c4_1, aj1, rb1, ra1);
            u64 A2 = iou_word(c4_2, aj2, rb0, ra0);
            u64 B2 = iou_word(c4_2, aj2, rb1, ra1);
            u64 A3 = iou_word(c4_3, aj3, rb0, ra0);
            u64 B3 = iou_word(c4_3, aj3, rb1, ra1);
            int row0 = rglob0 + q;      // even
            if (lane == 0) {
                u64* d0 = Mb + (size_t)row0 * MROW + w0;        // 32 B aligned
                ((ulonglong2*)d0)[0] = make_ulonglong2(A0, A1);
                ((ulonglong2*)d0)[1] = make_ulonglong2(A2, A3);
                u64* d1 = d0 + MROW;
                ((ulonglong2*)d1)[0] = make_ulonglong2(B0, B1);
                ((ulonglong2*)d1)[1] = make_ulonglong2(B2, B3);
            }
        }
    } else {
        // ---- general path: diag masking on all words (R16 body)
        int nrows = min(32, NMS_K - rglob0);   // even
        int sh_base = rglob0 - w0 * 64;        // wave-uniform
#pragma unroll 2
        for (int q = 0; q < nrows; q += 2) {
            int lr = lr0 + q;
            float4 rb0 = rbox[lr], rb1 = rbox[lr + 1];
            float  ra0 = rarea[lr], ra1 = rarea[lr + 1];
            u64 A0 = iou_word(c4_0, aj0, rb0, ra0);
            u64 B0 = iou_word(c4_0, aj0, rb1, ra1);
            u64 A1 = iou_word(c4_1, aj1, rb0, ra0);
            u64 B1 = iou_word(c4_1, aj1, rb1, ra1);
            u64 A2 = iou_word(c4_2, aj2, rb0, ra0);
            u64 B2 = iou_word(c4_2, aj2, rb1, ra1);
            u64 A3 = iou_word(c4_3, aj3, rb0, ra0);
            u64 B3 = iou_word(c4_3, aj3, rb1, ra1);
            int sh = sh_base + q;              // wave-uniform (SALU)
            A0 = diag_mask(A0, sh);       B0 = diag_mask(B0, sh + 1);
            A1 = diag_mask(A1, sh - 64);  B1 = diag_mask(B1, sh - 63);
            A2 = diag_mask(A2, sh - 128); B2 = diag_mask(B2, sh - 127);
            A3 = diag_mask(A3, sh - 192); B3 = diag_mask(B3, sh - 191);
            int row0 = rglob0 + q;      // even
            if (lane == 0) {
                u64* d0 = Mb + (size_t)row0 * MROW + w0;
                ((ulonglong2*)d0)[0] = make_ulonglong2(A0, A1);
                ((ulonglong2*)d0)[1] = make_ulonglong2(A2, A3);
                u64* d1 = d0 + MROW;
                ((ulonglong2*)d1)[0] = make_ulonglong2(B0, B1);
                ((ulonglong2*)d1)[1] = make_ulonglong2(B2, B3);
            }
        }
    }
}

// -------- greedy scan: single barrier per word ----------------------------
// R22 lazy-prefetch structure; R23 CUT guards with bit-identical slow path.
__global__ __launch_bounds__(1024) void maskscan_kernel(
        const float* __restrict__ cscore, const float* __restrict__ cbox,
        const float* __restrict__ carea,
        const unsigned int* __restrict__ cnt, const u64* __restrict__ M,
        float* __restrict__ out) {
    int b = blockIdx.x;
    int tid = threadIdx.x, lane = tid & 63, wv = tid >> 6;  // 16 waves
    int nv = min((int)cnt[b * CNTSTRIDE], NMS_K);
    const u64* MB = M + (size_t)b * NKPAD * MROW;   // [row][word]
    const float4* __restrict__ cbp = (const float4*)cbox + (size_t)b * NMS_K;
    const float*  __restrict__ cap = carea + (size_t)b * NMS_K;
    float* outb = out + (size_t)b * 2 * TOPK * 5;
    __shared__ unsigned int supp4[4];   // [par*2 + {lo,hi}], double-buffered
    __shared__ u64 dbuf[2][64];
    __shared__ short allp[TOPK];
    __shared__ int emitted_sh;
    for (int i = tid; i < 2 * TOPK * 5; i += 1024) outb[i] = 0.f;  // zero out
    if (tid < 4) supp4[tid] = 0u;
    if (tid == 0) emitted_sh = 0;
    if (wv == 1) dbuf[0][lane] = MB[(size_t)lane * MROW];  // diag(0), 0 < CUT
    __syncthreads();
    int emitted = 0;
    int nwords = (nv + 63) >> 6;
    u64 colw_prev = 0ull;     // wave0: word w+1 of rows w*64+lane, per lane
    u64 pickprev  = 0ull;     // wave0: pickmask of word w-1
    for (int w = 0; w < nwords; w++) {
        int par = w & 1;
        if (wv == 0) {
            u64 colw;
            if (w + 1 < CUT) {
                colw = MB[(size_t)(w * 64 + lane) * MROW + (w + 1)];
            } else {
                int rc = min(w * 64 + lane, NMS_K - 1);
                colw = row_word_slow(cbp, cap, cbp[rc], cap[rc], w + 1);
            }
            u64 D = dbuf[par][lane];
            u64 sup = ((u64)supp4[2 * par + 1] << 32) | (u64)supp4[2 * par];
            if (lane == 0) {            // recycle slot for word w+2's ORs
                supp4[2 * par] = 0u;
                supp4[2 * par + 1] = 0u;
            }
            u64 x = ((pickprev >> lane) & 1ull) ? colw_prev : 0ull;
#pragma unroll
            for (int m = 1; m < 64; m <<= 1) x |= shfl64_xor(x, m);
            sup |= x;
            int base = w * 64, rem = nv - base;
            u64 valid = (rem >= 64) ? ~0ull : ((1ull << rem) - 1ull);
            u64 alive = valid & ~sup;
            u64 nz = __ballot(D != 0ull);
            u64 pickmask = 0ull;
            while (alive) {
                u64 blockers = alive & nz;
                if (!blockers) { pickmask |= alive; break; }
                int nb = __builtin_ctzll(blockers);
                u64 mle = (nb >= 63) ? ~0ull : ((1ull << (nb + 1)) - 1ull);
                pickmask |= alive & mle;    // free run + the blocker itself
                u64 rw = shfl64(D, nb);     // blocker's in-word suppressions
                alive &= ~mle;
                alive &= ~rw;
            }
            int room = TOPK - emitted;
            int pc = __popcll(pickmask);
            while (pc > room) {             // keep lowest `room` picks
                pickmask &= ~(1ull << (63 - __builtin_clzll(pickmask)));
                pc--;
            }
            if (lane == 0) emitted_sh = emitted + pc;
            if ((pickmask >> lane) & 1ull) {
                int rank = (int)__popcll(pickmask & ((1ull << lane) - 1ull));
                allp[emitted + rank] = (short)(base + lane);
            }
            pickprev = pickmask;
            colw_prev = colw;
        } else if (wv == 1) {
            if (w + 1 < nwords) {           // diag(w+1) -> other dbuf half
                int W = w + 1;
                u64 dpre;
                if (W < CUT) {
                    dpre = MB[(size_t)(W * 64 + lane) * MROW + W];
                } else {
                    int rc = min(W * 64 + lane, NMS_K - 1);
                    dpre = diag_mask(
                        row_word_slow(cbp, cap, cbp[rc], cap[rc], W), lane);
                }
                dbuf[W & 1][lane] = dpre;
            }
        } else {
            // lazy prefetch: sup for word w+1 from picks emitted before w
            int i = (wv - 2) * 64 + lane;   // covers 0..895 >= TOPK
            u64 v = 0ull;
            if (i < emitted) {
                int pr = allp[i];
                if (w + 1 < CUT)
                    v = MB[(size_t)pr * MROW + (w + 1)];
                else
                    v = row_word_slow(cbp, cap, cbp[pr], cap[pr], w + 1);
            }
#pragma unroll
            for (int m = 1; m < 64; m <<= 1) v |= shfl64_xor(v, m);
            if (lane == 0 && v) {
                atomicOr(&supp4[2 * (par ^ 1)],     (unsigned int)v);
                atomicOr(&supp4[2 * (par ^ 1) + 1], (unsigned int)(v >> 32));
            }
        }
        __syncthreads();                   // the single barrier per word
        emitted = emitted_sh;
        if (emitted >= TOPK) break;
    }
    // final emit: all picks at once, 16 waves
    for (int t = tid; t < emitted; t += 1024) {
        int p = allp[t];
        float sc  = cscore[b * NMS_K + p];
        float4 bx = ((const float4*)cbox)[(size_t)b * NMS_K + p];
        float* o = outb + (size_t)(TOPK + t) * 5;   // class 1 rows
        o[0] = sc; o[1] = bx.x; o[2] = bx.y; o[3] = bx.z; o[4] = bx.w;
    }
}

extern "C" void kernel_launch(void* const* d_in, const int* in_sizes, int n_in,
                              void* d_out, int out_size, void* d_ws, size_t ws_size,
                              hipStream_t stream) {
    const float* loc    = (const float*)d_in[0];
    const float* conf   = (const float*)d_in[1];
    const float* priors = (const float*)d_in[2];
    float* out = (float*)d_out;

    char* ws = (char*)d_ws;
    size_t off = 0;
    unsigned int* hist = (unsigned int*)(ws + off);   off += (size_t)BATCH * HBINS * 4; // 32 KiB
    unsigned int* cnt  = (unsigned int*)(ws + off);   off += (size_t)BATCH * CNTSTRIDE * 4; // 1 KiB padded
    size_t zero_bytes = off;                          // hist + cnt only
    u64* keys  = (u64*)(ws + off);                    off += (size_t)BATCH * SORT_N * 8;
    u64* keys2 = (u64*)(ws + off);                    off += (size_t)BATCH * SORT_N * 8;
    float* cscore = (float*)(ws + off);               off += (size_t)BATCH * NMS_K * 4;
    float* cbox   = (float*)(ws + off);               off += (size_t)BATCH * NMS_K * 16;
    float* carea  = (float*)(ws + off);               off += (size_t)BATCH * NMS_K * 4;
    u64* M = (u64*)(ws + off);                        off += (size_t)BATCH * NKPAD * MROW * 8; // 26.2 MB, row-major
    float* sraw = (float*)M;   // alias: sraw dead before maskbuild writes M

    hipMemsetAsync(d_ws, 0, zero_bytes, stream);

    score_hist_kernel<<<dim3(64, BATCH), 256, 0, stream>>>(conf, hist, sraw);
    compact_kernel<<<dim3(64, BATCH), 256, 0, stream>>>(sraw, hist, keys, cnt);
    sortmerge4k_kernel<<<dim3(2, BATCH), 1024, 0, stream>>>(keys, keys2, cnt);
    merge2_decode_kernel<<<dim3(20, BATCH), 256, 0, stream>>>(keys2, loc, priors, cscore, cbox, carea);
    maskbuild_kernel<<<dim3(72, BATCH), 256, 0, stream>>>(cbox, carea, M);
    maskscan_kernel<<<BATCH, 1024, 0, stream>>>(cscore, cbox, carea, cnt, M, out);
}

// Round 21
// 160.842 us; speedup vs baseline: 1.0918x; 1.0918x over previous
//
#include <hip/hip_runtime.h>
#include <stdint.h>

#pragma clang fp contract(off)

#define NPRI   136500
#define BATCH  8
#define NMS_K  5000
#define NKPAD  5120      // padded row count
#define TOPK   750
#define SORT_N 8192
#define HBINS  1024      // top16 float bits of s in (0.05,1] span [0x3D4C,0x3F80]
#define HOFF   0x3D40
#define MROW   80        // u64 words per mask row (79 used, padded)
#define CNTSTRIDE 32     // 128 B between per-batch counters (line padding)
#define CUT    32        // M built only for words < CUT (cols < 2048)

typedef unsigned long long u64;

__device__ __forceinline__ u64 shfl64(u64 v, int src) {
    int lo = __shfl((int)(unsigned)(v & 0xffffffffull), src);
    int hi = __shfl((int)(unsigned)(v >> 32), src);
    return ((u64)(unsigned)hi << 32) | (u64)(unsigned)lo;
}
__device__ __forceinline__ u64 shfl64_xor(u64 v, int m) {
    int lo = __shfl_xor((int)(unsigned)(v & 0xffffffffull), m);
    int hi = __shfl_xor((int)(unsigned)(v >> 32), m);
    return ((u64)(unsigned)hi << 32) | (u64)(unsigned)lo;
}

// R12 (verified absmax=0): exact suppression test, pure f32, branchless.
// suppress <=> RN(inter/uni) > 0.3f <=> inter > (0.3f + 2^-26)*uni in reals.
// Two single-rounding FMAs: u = RN(inter-0.3f*uni); d = RN(u-2^-26*uni).
// d>0 <=> true condition (monotonicity + quantum-grid argument).
__device__ __forceinline__ bool iou_sup(float4 c4, float aj,
                                        float4 rbx, float ra) {
    float xx1 = fmaxf(c4.x, rbx.x);
    float yy1 = fmaxf(c4.y, rbx.y);
    float xx2 = fminf(c4.z, rbx.z);
    float yy2 = fminf(c4.w, rbx.w);
    float iw = fmaxf(xx2 - xx1, 0.0f);
    float ih = fmaxf(yy2 - yy1, 0.0f);
    float inter = iw * ih;
    float uni = (aj - inter) + ra;      // (area_col - inter) + area_row
    float u = fmaf(-0.3f, uni, inter);
    float d = fmaf(-1.4901161193847656e-8f, uni, u);   // 2^-26 exact in f32
    return d > 0.0f;
}
__device__ __forceinline__ u64 iou_word(float4 c4, float aj,
                                        float4 rbx, float ra) {
    return __ballot(iou_sup(c4, aj, rbx, ra));
}

// diag/below-diag mask for a word given sh = row - 64*w (wave-uniform SALU)
__device__ __forceinline__ u64 diag_mask(u64 word, int sh) {
    if (sh >= 0)
        word &= (sh >= 63) ? 0ull : (~0ull << (sh + 1));
    return word;
}

// R23 slow path (words >= CUT, typically never executed: scan ends ~word
// 13): per-lane serial row-word from cbox/carea, SAME exact test and SAME
// operand order as maskbuild => bit-identical to what maskbuild would have
// stored. rbx/ra = ROW box/area; W = column word.
__device__ u64 row_word_slow(const float4* __restrict__ cbp,
                             const float* __restrict__ cap,
                             float4 rbx, float ra, int W) {
    int jbase = W << 6;
    u64 word = 0ull;
    for (int jj = 0; jj < 64; ++jj) {
        int jc = min(jbase + jj, NMS_K - 1);
        if (iou_sup(cbp[jc], cap[jc], rbx, ra)) word |= (1ull << jj);
    }
    return word;
}

// -------- softmax score (cached to sraw) + LDS histogram of top-16 bits ---
__global__ __launch_bounds__(256) void score_hist_kernel(
        const float* __restrict__ conf, unsigned int* __restrict__ hist,
        float* __restrict__ sraw) {
    int b = blockIdx.y;
    __shared__ unsigned int h[HBINS];
    for (int i = threadIdx.x; i < HBINS; i += 256) h[i] = 0;
    __syncthreads();
    for (int p = blockIdx.x * 256 + threadIdx.x; p < NPRI; p += 64 * 256) {
        float2 c = ((const float2*)conf)[(size_t)b * NPRI + p];
        float m  = fmaxf(c.x, c.y);
        float e0 = expf(c.x - m), e1 = expf(c.y - m);
        float s  = e1 / (e0 + e1);
        sraw[(size_t)b * NPRI + p] = s;
        if (s > 0.05f) {
            int bin = (int)(__float_as_uint(s) >> 16) - HOFF;
            bin = min(max(bin, 0), HBINS - 1);
            atomicAdd(&h[bin], 1u);
        }
    }
    __syncthreads();
    for (int i = threadIdx.x; i < HBINS; i += 256) {
        unsigned int v = h[i];
        if (v) atomicAdd(&hist[b * HBINS + i], v);
    }
}

// -------- compact candidates: grid-stride, LDS staging, 1 atomic/block ----
// R21 verified core. R26: threshold bin computed IN-KERNEL per block
// (replaces scan_kernel dispatch); deterministic => output byte-identical.
__global__ __launch_bounds__(256) void compact_kernel(
        const float* __restrict__ sraw, const unsigned int* __restrict__ hist,
        u64* __restrict__ keys, unsigned int* __restrict__ cnt) {
    int b = blockIdx.y;
    int tid = threadIdx.x;
    int lane = tid & 63;
    __shared__ u64 buf[2304];           // 18 KiB; >= 9 iters * 256 worst case
    __shared__ unsigned int hsum[256];  // chunk sums -> suffix sums
    __shared__ int best_sh;
    __shared__ unsigned int nloc;
    __shared__ unsigned int base_sh;
    // ---- compute tbin (replicated; identical in all blocks) ----
    const unsigned int* hb = hist + b * HBINS;
    int t4 = tid * 4;
    unsigned int h0 = hb[t4], h1 = hb[t4 + 1], h2 = hb[t4 + 2], h3 = hb[t4 + 3];
    hsum[tid] = h0 + h1 + h2 + h3;
    if (tid == 0) { best_sh = 0; nloc = 0; }
    __syncthreads();
    for (int o = 1; o < 256; o <<= 1) {     // reverse inclusive chunk scan
        unsigned int add = (tid + o < 256) ? hsum[tid + o] : 0u;
        __syncthreads();
        hsum[tid] += add;
        __syncthreads();
    }
    unsigned int nxt = (tid + 1 < 256) ? hsum[tid + 1] : 0u;  // suffix(t4+4)
    unsigned int s3 = h3 + nxt;
    unsigned int s2 = h2 + s3;
    unsigned int s1 = h1 + s2;
    unsigned int s0 = h0 + s1;
    int cand = -1;                          // suffix non-increasing in bin
    if (s3 >= (unsigned)NMS_K) cand = t4 + 3;
    else if (s2 >= (unsigned)NMS_K) cand = t4 + 2;
    else if (s1 >= (unsigned)NMS_K) cand = t4 + 1;
    else if (s0 >= (unsigned)NMS_K) cand = t4;
    if (cand > 0) atomicMax(&best_sh, cand);
    __syncthreads();
    int tb = best_sh;
    // ---- R21 compact body ----
    for (int p = blockIdx.x * 256 + tid; p < NPRI; p += 64 * 256) {
        float s = sraw[(size_t)b * NPRI + p];
        bool pass = false;
        unsigned int bits = 0;
        if (s > 0.05f) {
            bits = __float_as_uint(s);
            int bin = (int)(bits >> 16) - HOFF;
            bin = min(max(bin, 0), HBINS - 1);
            pass = (bin >= tb);
        }
        u64 bal = __ballot(pass);
        int rank = (int)__popcll(bal & ((1ull << lane) - 1ull));
        unsigned int wbase = 0;
        if (lane == 0 && bal)
            wbase = atomicAdd(&nloc, (unsigned)__popcll(bal));
        wbase = (unsigned)__shfl((int)wbase, 0);
        if (pass)
            buf[wbase + rank] = ((u64)bits << 32) | (u64)(~(unsigned int)p);
    }
    __syncthreads();
    unsigned int tot = nloc;
    if (tid == 0)
        base_sh = tot ? atomicAdd(&cnt[b * CNTSTRIDE], tot) : 0u;
    __syncthreads();
    unsigned int base = base_sh;
    for (unsigned int i = tid; i < tot; i += 256) {
        unsigned int pos = base + i;
        if (pos < SORT_N)
            keys[(size_t)b * SORT_N + pos] = buf[i];
    }
}

// -------- R28/R29 (verified 162.5 us): 2048-chunk sort ---------------------
// Register bitonic (0 barriers) + 5 LDS merge-path rounds with 2 hand-
// interleaved branchless fixed-step searches per thread. Byte-identical
// keys2 vs the original sort1k+merge0 chain (deterministic on multisets).
__global__ __launch_bounds__(1024) void sortmerge2k_kernel(
        const u64* __restrict__ keys, u64* __restrict__ keys2,
        const unsigned int* __restrict__ cnt) {
    int b = blockIdx.y, c = blockIdx.x;     // chunk 0..3 (2048 each)
    int tid = threadIdx.x;
    int lane = tid & 63;
    int wv = tid >> 6;                      // 0..15
    int n = min((int)cnt[b * CNTSTRIDE], SORT_N);
    int base = c * 2048;
    if (base >= n) {                        // all-zero chunk: skip the sort
        for (int i = tid; i < 2048; i += 1024)
            keys2[(size_t)b * SORT_N + base + i] = 0ull;
        return;
    }
    __shared__ u64 k[2048];                 // 16 KiB
    __shared__ u64 k2[2048];                // 16 KiB (ping-pong)
    // ---- stage A: 32 runs of 64, register bitonic per wave (2/wave) ----
    for (int ch = wv; ch < 32; ch += 16) {
        int idx = base + ch * 64 + lane;
        u64 v = (idx < n) ? keys[(size_t)b * SORT_N + idx] : 0ull;
#pragma unroll
        for (int kk = 2; kk <= 64; kk <<= 1) {
#pragma unroll
            for (int j = kk >> 1; j > 0; j >>= 1) {
                u64 o = shfl64_xor(v, j);
                bool low  = (lane & j) == 0;          // partner above
                bool desc = (lane & kk) == 0;         // kk=64 -> always true
                u64 mx = (v >= o) ? v : o;
                u64 mn = (v >= o) ? o : v;
                v = desc ? (low ? mx : mn) : (low ? mn : mx);
            }
        }
        k[ch * 64 + lane] = v;
    }
    __syncthreads();
    // ---- stage B: 5 merge-path rounds, 64 -> 2048, interleaved chains ---
    u64* src = k;
    u64* dst = k2;
    for (int L = 64; L < 2048; L <<= 1) {
        int o0 = tid, o1 = tid + 1024;
        int pair0 = o0 / (2 * L), oo0 = o0 - pair0 * 2 * L;
        int pair1 = o1 / (2 * L), oo1 = o1 - pair1 * 2 * L;
        const u64* A0 = src + pair0 * 2 * L; const u64* B0 = A0 + L;
        const u64* A1 = src + pair1 * 2 * L; const u64* B1 = A1 + L;
        int lo0 = max(0, oo0 - L), hi0 = min(oo0, L);
        int lo1 = max(0, oo1 - L), hi1 = min(oo1, L);
#pragma unroll
        for (int s = 0; s < 12; ++s) {      // 12 >= ceil(log2(1024+1))
            bool lv0 = lo0 < hi0;
            bool lv1 = lo1 < hi1;
            int m0 = (lo0 + hi0 + 1) >> 1;
            int m1 = (lo1 + hi1 + 1) >> 1;
            u64 a0 = A0[max(m0 - 1, 0)];
            u64 b0 = B0[min(max(oo0 - m0, 0), L - 1)];
            u64 a1 = A1[max(m1 - 1, 0)];
            u64 b1 = B1[min(max(oo1 - m1, 0), L - 1)];
            bool ok0 = (oo0 - m0 >= L) || (a0 >= b0);
            bool ok1 = (oo1 - m1 >= L) || (a1 >= b1);
            lo0 = (lv0 && ok0)  ? m0     : lo0;
            hi0 = (lv0 && !ok0) ? m0 - 1 : hi0;
            lo1 = (lv1 && ok1)  ? m1     : lo1;
            hi1 = (lv1 && !ok1) ? m1 - 1 : hi1;
        }
        {
            int i = lo0, j = oo0 - lo0;
            u64 v;
            if (j >= L) v = A0[i];
            else if (i >= L) v = B0[j];
            else v = (A0[i] >= B0[j]) ? A0[i] : B0[j];
            dst[o0] = v;
        }
        {
            int i = lo1, j = oo1 - lo1;
            u64 v;
            if (j >= L) v = A1[i];
            else if (i >= L) v = B1[j];
            else v = (A1[i] >= B1[j]) ? A1[i] : B1[j];
            dst[o1] = v;
        }
        __syncthreads();
        u64* t = src; src = dst; dst = t;
    }
    for (int i = tid; i < 2048; i += 1024)
        keys2[(size_t)b * SORT_N + base + i] = src[i];
}

// -------- merge-path stage 1: (2048,2048)->4096 desc, two pairs/batch -----
__global__ __launch_bounds__(256) void merge1_kernel(
        const u64* __restrict__ keys2, u64* __restrict__ keys) {
    int b = blockIdx.y;
    int o = blockIdx.x * 256 + threadIdx.x;   // 0..8191
    int pair = o >> 12;
    int oo = o & 4095;
    const u64* A  = keys2 + (size_t)b * SORT_N + pair * 4096;
    const u64* Bp = A + 2048;
    int lo = max(0, oo - 2048), hi = min(oo, 2048);
    while (lo < hi) {
        int mid = (lo + hi + 1) >> 1;
        bool ok = (oo - mid >= 2048) || (A[mid - 1] >= Bp[oo - mid]);
        if (ok) lo = mid; else hi = mid - 1;
    }
    int i = lo, j = oo - lo;
    u64 v;
    if (j >= 2048) v = A[i];
    else if (i >= 2048) v = Bp[j];
    else v = (A[i] >= Bp[j]) ? A[i] : Bp[j];
    keys[(size_t)b * SORT_N + pair * 4096 + oo] = v;
}

// -------- merge-path stage 2 fused with decode: (4096,4096)->rows 0..4999 -
__global__ __launch_bounds__(256) void merge2_decode_kernel(
        const u64* __restrict__ keys,
        const float* __restrict__ loc, const float* __restrict__ priors,
        float* __restrict__ cscore, float* __restrict__ cbox,
        float* __restrict__ carea) {
    int b = blockIdx.y;
    int o = blockIdx.x * 256 + threadIdx.x;   // 0..5119
    const u64* A  = keys + (size_t)b * SORT_N;
    const u64* Bp = A + 4096;
    int lo = max(0, o - 4096), hi = min(o, 4096);
    while (lo < hi) {
        int mid = (lo + hi + 1) >> 1;
        bool ok = (o - mid >= 4096) || (A[mid - 1] >= Bp[o - mid]);
        if (ok) lo = mid; else hi = mid - 1;
    }
    int i = lo, j = o - lo;
    u64 key;
    if (j >= 4096) key = A[i];
    else if (i >= 4096) key = Bp[j];
    else key = (A[i] >= Bp[j]) ? A[i] : Bp[j];
    if (o >= NMS_K) return;                   // only rows 0..4999 consumed
    float sc; int idx;
    if (key != 0ull) {
        sc  = __uint_as_float((unsigned int)(key >> 32));
        idx = (int)(~(unsigned int)key);
    } else { sc = -1.0f; idx = 0; }
    cscore[b * NMS_K + o] = sc;
    float x1 = 0.f, y1 = 0.f, x2 = 0.f, y2 = 0.f, ar = 0.f;
    if (key != 0ull) {
        const float* l  = loc + ((size_t)b * NPRI + idx) * 4;
        const float* pr = priors + (size_t)idx * 4;
        float lx = l[0], ly = l[1], lw = l[2], lh = l[3];
        float pcx = pr[0], pcy = pr[1], pw = pr[2], ph = pr[3];
        float cx = pcx + (lx * 0.1f) * pw;
        float cy = pcy + (ly * 0.1f) * ph;
        float wd = pw * expf(lw * 0.2f);
        float ht = ph * expf(lh * 0.2f);
        x1 = cx - wd * 0.5f;  y1 = cy - ht * 0.5f;
        x2 = x1 + wd;         y2 = y1 + ht;
        ar = (x2 - x1) * (y2 - y1);
    }
    float* cb = cbox + ((size_t)b * NMS_K + o) * 4;
    cb[0] = x1; cb[1] = y1; cb[2] = x2; cb[3] = y2;
    carea[b * NMS_K + o] = ar;
}

// -------- ROW-MAJOR upper-triangle suppression mask: M[b][row][w] --------
// R20 verified config; R23: only words < CUT built. Scan consumes words <=
// ~14 for this data; words >= CUT computed on-the-fly in maskscan if needed.
__global__ __launch_bounds__(256, 4) void maskbuild_kernel(
        const float* __restrict__ cbox, const float* __restrict__ carea,
        u64* __restrict__ M) {
    int b   = blockIdx.y;
    int bid = blockIdx.x;               // 0..71 (CUT/4 quads)
    int wgq, rb;
    if (bid >= 380) { wgq = 19; rb = bid - 380; }
    else {
        int w = (int)((sqrtf((float)(4 * bid + 5)) - 1.0f) * 0.5f);
        while (w * (w + 1) > bid) w--;
        while ((w + 1) * (w + 2) <= bid) w++;
        wgq = w; rb = bid - w * (w + 1);    // rb <= 2*wgq+1 by construction
    }
    int tid  = threadIdx.x;
    int lane = tid & 63;
    int wv   = __builtin_amdgcn_readfirstlane(tid >> 6);  // 0..3, scalar
    int w0   = wgq * 4;
    int rowbase = rb * 128;

    __shared__ float4 rbox[128];        // 2 KiB
    __shared__ float  rarea[128];       // 0.5 KiB
    if (tid < 128) {
        int i  = rowbase + tid;
        int ic = min(i, NMS_K - 1);     // rows >= NMS_K: dup, masked downstream
        rbox[tid]  = ((const float4*)cbox)[(size_t)b * NMS_K + ic];
        rarea[tid] = carea[(size_t)b * NMS_K + ic];
    }
    // 4 column-words in registers: lane = column j of word w0+k
    const float4* __restrict__ cbp = (const float4*)cbox + (size_t)b * NMS_K;
    const float*  __restrict__ cap = carea + (size_t)b * NMS_K;
    int j0 = w0 * 64 + lane;
    float4 c4_0 = cbp[min(j0,       NMS_K - 1)];
    float4 c4_1 = cbp[min(j0 +  64, NMS_K - 1)];
    float4 c4_2 = cbp[min(j0 + 128, NMS_K - 1)];
    float4 c4_3 = cbp[min(j0 + 192, NMS_K - 1)];
    float aj0 = cap[min(j0,       NMS_K - 1)];
    float aj1 = cap[min(j0 +  64, NMS_K - 1)];
    float aj2 = cap[min(j0 + 128, NMS_K - 1)];
    float aj3 = cap[min(j0 + 192, NMS_K - 1)];
    __syncthreads();                    // the only barrier; exits below OK

    int lr0 = 32 * wv;                  // this wave's local row base
    int rglob0 = rowbase + lr0;
    if (rglob0 >= NMS_K) return;        // wave entirely past the last row

    u64* __restrict__ Mb = M + (size_t)b * NKPAD * MROW;  // row-major

    if (rglob0 + 31 < w0 * 64) {
        // ---- pure-upper fast path: no diag masking, fixed 16-pair trip.
#pragma unroll 2
        for (int q = 0; q < 32; q += 2) {
            int lr = lr0 + q;
            float4 rb0 = rbox[lr], rb1 = rbox[lr + 1];
            float  ra0 = rarea[lr], ra1 = rarea[lr + 1];
            u64 A0 = iou_word(c4_0, aj0, rb0, ra0);
            u64 B0 = iou_word(c4_0, aj0, rb1, ra1);
            u64 A1 = iou_word(c4_1, aj1, rb0, ra0);
            u64 B1 = iou_word(c4_1, aj1, rb1, ra1);
            u64 A2 = iou_word(c4_2, aj2, rb0, ra0);
            u64 B2 = iou_word(c4_2, aj2, rb1, ra1);
            u64 A3 = iou_word(c4_3, aj3, rb0, ra0);
            u64 B3 = iou_word(c4_3, aj3, rb1, ra1);
            int row0 = rglob0 + q;      // even
            if (lane == 0) {
                u64* d0 = Mb + (size_t)row0 * MROW + w0;        // 32 B aligned
                ((ulonglong2*)d0)[0] = make_ulonglong2(A0, A1);
                ((ulonglong2*)d0)[1] = make_ulonglong2(A2, A3);
                u64* d1 = d0 + MROW;
                ((ulonglong2*)d1)[0] = make_ulonglong2(B0, B1);
                ((ulonglong2*)d1)[1] = make_ulonglong2(B2, B3);
            }
        }
    } else {
        // ---- general path: diag masking on all words (R16 body)
        int nrows = min(32, NMS_K - rglob0);   // even
        int sh_base = rglob0 - w0 * 64;        // wave-uniform
#pragma unroll 2
        for (int q = 0; q < nrows; q += 2) {
            int lr = lr0 + q;
            float4 rb0 = rbox[lr], rb1 = rbox[lr + 1];
            float  ra0 = rarea[lr], ra1 = rarea[lr + 1];
            u64 A0 = iou_word(c4_0, aj0, rb0, ra0);
            u64 B0 = iou_word(c4_0, aj0, rb1, ra1);
            u64 A1 = iou_word(c4_1, aj1, rb0, ra0);
            u64 B1 = iou_word(c4_1, aj1, rb1, ra1);
            u64 A2 = iou_word(c4_2, aj2, rb0, ra0);
            u64 B2 = iou_word(c4_2, aj2, rb1, ra1);
            u64 A3 = iou_word(c4_3, aj3, rb0, ra0);
            u64 B3 = iou_word(c4_3, aj3, rb1, ra1);
            int sh = sh_base + q;              // wave-uniform (SALU)
            A0 = diag_mask(A0, sh);       B0 = diag_mask(B0, sh + 1);
            A1 = diag_mask(A1, sh - 64);  B1 = diag_mask(B1, sh - 63);
            A2 = diag_mask(A2, sh - 128); B2 = diag_mask(B2, sh - 127);
            A3 = diag_mask(A3, sh - 192); B3 = diag_mask(B3, sh - 191);
            int row0 = rglob0 + q;      // even
            if (lane == 0) {
                u64* d0 = Mb + (size_t)row0 * MROW + w0;
                ((ulonglong2*)d0)[0] = make_ulonglong2(A0, A1);
                ((ulonglong2*)d0)[1] = make_ulonglong2(A2, A3);
                u64* d1 = d0 + MROW;
                ((ulonglong2*)d1)[0] = make_ulonglong2(B0, B1);
                ((ulonglong2*)d1)[1] = make_ulonglong2(B2, B3);
            }
        }
    }
}

// -------- greedy scan: single barrier per word ----------------------------
// R22 lazy-prefetch structure; R23 CUT guards with bit-identical slow path.
__global__ __launch_bounds__(1024) void maskscan_kernel(
        const float* __restrict__ cscore, const float* __restrict__ cbox,
        const float* __restrict__ carea,
        const unsigned int* __restrict__ cnt, const u64* __restrict__ M,
        float* __restrict__ out) {
    int b = blockIdx.x;
    int tid = threadIdx.x, lane = tid & 63, wv = tid >> 6;  // 16 waves
    int nv = min((int)cnt[b * CNTSTRIDE], NMS_K);
    const u64* MB = M + (size_t)b * NKPAD * MROW;   // [row][word]
    const float4* __restrict__ cbp = (const float4*)cbox + (size_t)b * NMS_K;
    const float*  __restrict__ cap = carea + (size_t)b * NMS_K;
    float* outb = out + (size_t)b * 2 * TOPK * 5;
    __shared__ unsigned int supp4[4];   // [par*2 + {lo,hi}], double-buffered
    __shared__ u64 dbuf[2][64];
    __shared__ short allp[TOPK];
    __shared__ int emitted_sh;
    for (int i = tid; i < 2 * TOPK * 5; i += 1024) outb[i] = 0.f;  // zero out
    if (tid < 4) supp4[tid] = 0u;
    if (tid == 0) emitted_sh = 0;
    if (wv == 1) dbuf[0][lane] = MB[(size_t)lane * MROW];  // diag(0), 0 < CUT
    __syncthreads();
    int emitted = 0;
    int nwords = (nv + 63) >> 6;
    u64 colw_prev = 0ull;     // wave0: word w+1 of rows w*64+lane, per lane
    u64 pickprev  = 0ull;     // wave0: pickmask of word w-1
    for (int w = 0; w < nwords; w++) {
        int par = w & 1;
        if (wv == 0) {
            u64 colw;
            if (w + 1 < CUT) {
                colw = MB[(size_t)(w * 64 + lane) * MROW + (w + 1)];
            } else {
                int rc = min(w * 64 + lane, NMS_K - 1);
                colw = row_word_slow(cbp, cap, cbp[rc], cap[rc], w + 1);
            }
            u64 D = dbuf[par][lane];
            u64 sup = ((u64)supp4[2 * par + 1] << 32) | (u64)supp4[2 * par];
            if (lane == 0) {            // recycle slot for word w+2's ORs
                supp4[2 * par] = 0u;
                supp4[2 * par + 1] = 0u;
            }
            u64 x = ((pickprev >> lane) & 1ull) ? colw_prev : 0ull;
#pragma unroll
            for (int m = 1; m < 64; m <<= 1) x |= shfl64_xor(x, m);
            sup |= x;
            int base = w * 64, rem = nv - base;
            u64 valid = (rem >= 64) ? ~0ull : ((1ull << rem) - 1ull);
            u64 alive = valid & ~sup;
            u64 nz = __ballot(D != 0ull);
            u64 pickmask = 0ull;
            while (alive) {
                u64 blockers = alive & nz;
                if (!blockers) { pickmask |= alive; break; }
                int nb = __builtin_ctzll(blockers);
                u64 mle = (nb >= 63) ? ~0ull : ((1ull << (nb + 1)) - 1ull);
                pickmask |= alive & mle;    // free run + the blocker itself
                u64 rw = shfl64(D, nb);     // blocker's in-word suppressions
                alive &= ~mle;
                alive &= ~rw;
            }
            int room = TOPK - emitted;
            int pc = __popcll(pickmask);
            while (pc > room) {             // keep lowest `room` picks
                pickmask &= ~(1ull << (63 - __builtin_clzll(pickmask)));
                pc--;
            }
            if (lane == 0) emitted_sh = emitted + pc;
            if ((pickmask >> lane) & 1ull) {
                int rank = (int)__popcll(pickmask & ((1ull << lane) - 1ull));
                allp[emitted + rank] = (short)(base + lane);
            }
            pickprev = pickmask;
            colw_prev = colw;
        } else if (wv == 1) {
            if (w + 1 < nwords) {           // diag(w+1) -> other dbuf half
                int W = w + 1;
                u64 dpre;
                if (W < CUT) {
                    dpre = MB[(size_t)(W * 64 + lane) * MROW + W];
                } else {
                    int rc = min(W * 64 + lane, NMS_K - 1);
                    dpre = diag_mask(
                        row_word_slow(cbp, cap, cbp[rc], cap[rc], W), lane);
                }
                dbuf[W & 1][lane] = dpre;
            }
        } else {
            // lazy prefetch: sup for word w+1 from picks emitted before w
            int i = (wv - 2) * 64 + lane;   // covers 0..895 >= TOPK
            u64 v = 0ull;
            if (i < emitted) {
                int pr = allp[i];
                if (w + 1 < CUT)
                    v = MB[(size_t)pr * MROW + (w + 1)];
                else
                    v = row_word_slow(cbp, cap, cbp[pr], cap[pr], w + 1);
            }
#pragma unroll
            for (int m = 1; m < 64; m <<= 1) v |= shfl64_xor(v, m);
            if (lane == 0 && v) {
                atomicOr(&supp4[2 * (par ^ 1)],     (unsigned int)v);
                atomicOr(&supp4[2 * (par ^ 1) + 1], (unsigned int)(v >> 32));
            }
        }
        __syncthreads();                   // the single barrier per word
        emitted = emitted_sh;
        if (emitted >= TOPK) break;
    }
    // final emit: all picks at once, 16 waves
    for (int t = tid; t < emitted; t += 1024) {
        int p = allp[t];
        float sc  = cscore[b * NMS_K + p];
        float4 bx = ((const float4*)cbox)[(size_t)b * NMS_K + p];
        float* o = outb + (size_t)(TOPK + t) * 5;   // class 1 rows
        o[0] = sc; o[1] = bx.x; o[2] = bx.y; o[3] = bx.z; o[4] = bx.w;
    }
}

extern "C" void kernel_launch(void* const* d_in, const int* in_sizes, int n_in,
                              void* d_out, int out_size, void* d_ws, size_t ws_size,
                              hipStream_t stream) {
    const float* loc    = (const float*)d_in[0];
    const float* conf   = (const float*)d_in[1];
    const float* priors = (const float*)d_in[2];
    float* out = (float*)d_out;

    char* ws = (char*)d_ws;
    size_t off = 0;
    unsigned int* hist = (unsigned int*)(ws + off);   off += (size_t)BATCH * HBINS * 4; // 32 KiB
    unsigned int* cnt  = (unsigned int*)(ws + off);   off += (size_t)BATCH * CNTSTRIDE * 4; // 1 KiB padded
    size_t zero_bytes = off;                          // hist + cnt only
    u64* keys  = (u64*)(ws + off);                    off += (size_t)BATCH * SORT_N * 8;
    u64* keys2 = (u64*)(ws + off);                    off += (size_t)BATCH * SORT_N * 8;
    float* cscore = (float*)(ws + off);               off += (size_t)BATCH * NMS_K * 4;
    float* cbox   = (float*)(ws + off);               off += (size_t)BATCH * NMS_K * 16;
    float* carea  = (float*)(ws + off);               off += (size_t)BATCH * NMS_K * 4;
    u64* M = (u64*)(ws + off);                        off += (size_t)BATCH * NKPAD * MROW * 8; // 26.2 MB, row-major
    float* sraw = (float*)M;   // alias: sraw dead before maskbuild writes M

    hipMemsetAsync(d_ws, 0, zero_bytes, stream);

    score_hist_kernel<<<dim3(64, BATCH), 256, 0, stream>>>(conf, hist, sraw);
    compact_kernel<<<dim3(64, BATCH), 256, 0, stream>>>(sraw, hist, keys, cnt);
    sortmerge2k_kernel<<<dim3(4, BATCH), 1024, 0, stream>>>(keys, keys2, cnt);
    merge1_kernel<<<dim3(32, BATCH), 256, 0, stream>>>(keys2, keys);
    merge2_decode_kernel<<<dim3(20, BATCH), 256, 0, stream>>>(keys, loc, priors, cscore, cbox, carea);
    maskbuild_kernel<<<dim3(72, BATCH), 256, 0, stream>>>(cbox, carea, M);
    maskscan_kernel<<<BATCH, 1024, 0, stream>>>(cscore, cbox, carea, cnt, M, out);
}